// Round 4
// baseline (30514.136 us; speedup 1.0000x reference)
//
#include <hip/hip_runtime.h>
#include <cstdint>
#include <cstddef>

#define TOK 16384
#define NE  8192

// output layout (all float32): loss | z_q(32,64,512) | perp | enc(16384,8192) | idx(16384)
#define O_ZQ   1
#define O_PERP 1048577
#define O_ENC  1048578
#define O_IDX  135266306

// ---------------------------------------------------------------------------
// K0: s_z per token + s_e per code (numpy 8-acc pairwise), init packed/hist
// ---------------------------------------------------------------------------
__global__ __launch_bounds__(256) void k_init(
    const float* __restrict__ z, const int* __restrict__ mask,
    const float* __restrict__ emb,
    unsigned long long* __restrict__ packed,
    float* __restrict__ s_z, float* __restrict__ s_e,
    int* __restrict__ hist) {
  int g = blockIdx.x * 256 + threadIdx.x;
  if (g < TOK) {
    int t = g, b = t >> 9, l = t & 511;
    const float* zp = z + (size_t)b * 32768 + l;
    float r[8];
#pragma unroll
    for (int j = 0; j < 8; ++j) { float v = zp[(size_t)j * 512]; r[j] = __fmul_rn(v, v); }
#pragma unroll
    for (int i = 8; i < 64; i += 8)
#pragma unroll
      for (int j = 0; j < 8; ++j) { float v = zp[(size_t)(i + j) * 512]; r[j] = __fadd_rn(r[j], __fmul_rn(v, v)); }
    float s = __fadd_rn(__fadd_rn(__fadd_rn(r[0], r[1]), __fadd_rn(r[2], r[3])),
                        __fadd_rn(__fadd_rn(r[4], r[5]), __fadd_rn(r[6], r[7])));
    s_z[t] = mask[t] ? s : 0.0f;
    packed[t] = ~0ull;
  } else if (g < TOK + NE) {
    int i = g - TOK;
    const float* ep = emb + (size_t)i * 64;
    float r[8];
#pragma unroll
    for (int j = 0; j < 8; ++j) { float v = ep[j]; r[j] = __fmul_rn(v, v); }
#pragma unroll
    for (int kk = 8; kk < 64; kk += 8)
#pragma unroll
      for (int j = 0; j < 8; ++j) { float v = ep[kk + j]; r[j] = __fadd_rn(r[j], __fmul_rn(v, v)); }
    float s = __fadd_rn(__fadd_rn(__fadd_rn(r[0], r[1]), __fadd_rn(r[2], r[3])),
                        __fadd_rn(__fadd_rn(r[4], r[5]), __fadd_rn(r[6], r[7])));
    s_e[i] = s;
    hist[i] = 0;
  }
}

// ---------------------------------------------------------------------------
// K1: distance GEMM. 128 thr (8 tg x 16 cg), tile 64 tok x 256 codes,
// per-thread 8x16, XOR-swizzled unpadded LDS (80 KB -> 2 blocks/CU).
// thread (tg,cg): tokens tg+8m (m 0..7), codes cg+16j (j 0..15).
// ---------------------------------------------------------------------------
__global__ __launch_bounds__(128) void k_search(
    const float* __restrict__ z, const int* __restrict__ mask,
    const float* __restrict__ emb,
    const float* __restrict__ s_z, const float* __restrict__ s_e,
    unsigned long long* __restrict__ packed,
    float* __restrict__ enc_out) {
  __shared__ __align__(16) float zs[64][64];   // [tok][k ^ ((tok&7)<<2)]
  __shared__ __align__(16) float es[256][64];  // [code][k ^ ((code&7)<<2)]

  const int tid = threadIdx.x;
  const int I0  = blockIdx.x * 256;
  const int T0  = blockIdx.y * 64;
  const int b   = T0 >> 9;
  const int l0  = T0 & 511;

  // ---- stage zs: coalesced global reads (per k, 64 contiguous l), b128 writes
  {
    const int tok = tid & 63;
    const int kh  = tid >> 6;                  // wave 0 -> k 0..31, wave 1 -> 32..63
    const int m   = mask[T0 + tok];
    const int xr  = (tok & 7) << 2;
#pragma unroll
    for (int it = 0; it < 8; ++it) {
      int k0 = kh * 32 + it * 4;
      float4 v;
      v.x = z[(size_t)b * 32768 + (size_t)(k0 + 0) * 512 + l0 + tok];
      v.y = z[(size_t)b * 32768 + (size_t)(k0 + 1) * 512 + l0 + tok];
      v.z = z[(size_t)b * 32768 + (size_t)(k0 + 2) * 512 + l0 + tok];
      v.w = z[(size_t)b * 32768 + (size_t)(k0 + 3) * 512 + l0 + tok];
      if (!m) v = make_float4(0.f, 0.f, 0.f, 0.f);
      *(float4*)&zs[tok][k0 ^ xr] = v;
    }
  }
  // ---- stage es: fully coalesced float4 reads, ~2-way-conflict b128 writes
  {
    const float4* e4 = (const float4*)(emb + (size_t)I0 * 64);
#pragma unroll
    for (int pass = 0; pass < 32; ++pass) {
      int g    = pass * 128 + tid;             // 0..4095 float4s
      int code = g >> 4;
      int k4   = g & 15;
      *(float4*)&es[code][(k4 * 4) ^ ((code & 7) << 2)] = e4[g];
    }
  }
  __syncthreads();

  const int tg = tid >> 4;   // 0..7
  const int cg = tid & 15;   // 0..15
  const int xz = tg << 2;                     // (token&7)<<2, token = tg+8m
  const int xe = (cg & 7) << 2;               // (code&7)<<2,  code = cg+16j

  // epilogue scalars, prefetched
  float szv[8], sev[16];
#pragma unroll
  for (int m = 0; m < 8; ++m) szv[m] = s_z[T0 + tg + 8 * m];
#pragma unroll
  for (int j = 0; j < 16; ++j) sev[j] = s_e[I0 + cg + 16 * j];

  float acc[8][16];
#pragma unroll
  for (int m = 0; m < 8; ++m)
#pragma unroll
    for (int j = 0; j < 16; ++j) acc[m][j] = 0.0f;

  float* encb = enc_out + (size_t)T0 * 8192 + I0;

#pragma unroll
  for (int kc = 0; kc < 64; kc += 4) {
    float4 zv[8], ev[16];
#pragma unroll
    for (int m = 0; m < 8; ++m) zv[m] = *(const float4*)&zs[tg + 8 * m][kc ^ xz];
#pragma unroll
    for (int j = 0; j < 16; ++j) ev[j] = *(const float4*)&es[cg + 16 * j][kc ^ xe];

    // fused metered zero-fill of the 64x256 enc tile (2 float4 stores/chunk)
    {
      int id0 = (kc >> 2) * 256 + tid;         // two ids: id0, id0+128
      int r0 = id0 >> 6, c0 = id0 & 63;
      int id1 = id0 + 128;
      int r1 = id1 >> 6, c1 = id1 & 63;
      const float4 zz = make_float4(0.f, 0.f, 0.f, 0.f);
      *(float4*)(encb + (size_t)r0 * 8192 + c0 * 4) = zz;
      *(float4*)(encb + (size_t)r1 * 8192 + c1 * 4) = zz;
    }

#pragma unroll
    for (int m = 0; m < 8; ++m)
#pragma unroll
      for (int j = 0; j < 16; ++j) {
        acc[m][j] = fmaf(zv[m].x, ev[j].x, acc[m][j]);
        acc[m][j] = fmaf(zv[m].y, ev[j].y, acc[m][j]);
        acc[m][j] = fmaf(zv[m].z, ev[j].z, acc[m][j]);
        acc[m][j] = fmaf(zv[m].w, ev[j].w, acc[m][j]);
      }
  }

  // ---- epilogue: d = fl(fl(sz+se) - fl(2*dot)); float argmin, j ascending
  // (strict < keeps earliest j = lowest global index on exact ties)
  float best_d[8];
  int   best_i[8];
#pragma unroll
  for (int m = 0; m < 8; ++m) { best_d[m] = __uint_as_float(0x7F800000u); best_i[m] = 0; }
#pragma unroll
  for (int j = 0; j < 16; ++j) {
    const int i = I0 + cg + 16 * j;
#pragma unroll
    for (int m = 0; m < 8; ++m) {
      float d = __fsub_rn(__fadd_rn(szv[m], sev[j]), __fmul_rn(2.0f, acc[m][j]));
      bool lt = d < best_d[m];
      best_d[m] = lt ? d : best_d[m];
      best_i[m] = lt ? i : best_i[m];
    }
  }

  // pack (ordered-bits(d)<<32 | idx), reduce across cg (lane bits 0..3), atomic
#pragma unroll
  for (int m = 0; m < 8; ++m) {
    unsigned int db = __float_as_uint(best_d[m]);
    db = ((int)db < 0) ? ~db : (db | 0x80000000u);
    unsigned long long p = ((unsigned long long)db << 32) | (unsigned int)best_i[m];
#pragma unroll
    for (int off = 1; off < 16; off <<= 1) {
      unsigned long long q = __shfl_xor(p, off, 64);
      p = (q < p) ? q : p;
    }
    if (cg == 0) atomicMin(&packed[T0 + tg + 8 * m], p);
  }
}

// ---------------------------------------------------------------------------
// K2: per-token finalize — coalesced (block = 64 consecutive tokens, 512 thr)
// ---------------------------------------------------------------------------
__global__ __launch_bounds__(512) void k_finalize(
    const float* __restrict__ z, const int* __restrict__ mask,
    const float* __restrict__ emb,
    const unsigned long long* __restrict__ packed,
    float* __restrict__ out_zq, float* __restrict__ out_enc,
    float* __restrict__ out_idx,
    int* __restrict__ hist, float* __restrict__ token_loss) {
  __shared__ float part[8][64];
  const int T0   = blockIdx.x * 64;
  const int lane = threadIdx.x & 63;
  const int w    = threadIdx.x >> 6;
  const int b    = T0 >> 9;
  const int l0   = T0 & 511;
  const int t    = T0 + lane;

  const int idx = (int)(unsigned int)(packed[t] & 0xFFFFFFFFu);

  const float* zb = z      + (size_t)b * 32768 + l0 + lane;
  float*       qb = out_zq + (size_t)b * 32768 + l0 + lane;

  float sq = 0.0f;
#pragma unroll
  for (int cc = 0; cc < 8; ++cc) {
    int c = w * 8 + cc;
    float zv   = zb[(size_t)c * 512];
    float e    = emb[(size_t)idx * 64 + c];
    float diff = __fsub_rn(e, zv);
    qb[(size_t)c * 512] = __fadd_rn(zv, diff);   // z + (z_q - z), bit-exact STE
    sq = fmaf(diff, diff, sq);
  }
  part[w][lane] = sq;
  __syncthreads();

  if (w == 0) {
    float s = __fadd_rn(
        __fadd_rn(__fadd_rn(part[0][lane], part[1][lane]),
                  __fadd_rn(part[2][lane], part[3][lane])),
        __fadd_rn(__fadd_rn(part[4][lane], part[5][lane]),
                  __fadd_rn(part[6][lane], part[7][lane])));
    token_loss[t] = mask[t] ? s : 0.0f;
    out_idx[t] = (float)idx;
    out_enc[(size_t)t * 8192 + idx] = 1.0f;
    atomicAdd(&hist[idx], 1);
  }
}

// ---------------------------------------------------------------------------
// K3a: partial reductions (64 blocks)
// ---------------------------------------------------------------------------
__global__ __launch_bounds__(256) void k_partial(
    const float* __restrict__ token_loss, const int* __restrict__ mask,
    const int* __restrict__ hist, float* __restrict__ partials) {
  __shared__ float sf[256], sm[256], sh[256];
  const int bb = blockIdx.x, tid = threadIdx.x;
  int ti = bb * 256 + tid;
  sf[tid] = token_loss[ti];
  sm[tid] = (float)mask[ti];
  float h = 0.f;
  if (tid < 128) {
    float pm = (float)hist[bb * 128 + tid] * (1.0f / 16384.0f);
    h = pm * logf(pm + 1e-10f);
  }
  sh[tid] = h;
  __syncthreads();
  for (int off = 128; off; off >>= 1) {
    if (tid < off) { sf[tid] += sf[tid + off]; sm[tid] += sm[tid + off]; sh[tid] += sh[tid + off]; }
    __syncthreads();
  }
  if (tid == 0) {
    partials[bb]       = sf[0];
    partials[64 + bb]  = sm[0];
    partials[128 + bb] = sh[0];
  }
}

// ---------------------------------------------------------------------------
// K3b: final scalars
// ---------------------------------------------------------------------------
__global__ __launch_bounds__(64) void k_final(
    const float* __restrict__ partials, float* __restrict__ out) {
  int tn = threadIdx.x;
  float lo = partials[tn], mc = partials[64 + tn], en = partials[128 + tn];
#pragma unroll
  for (int off = 32; off; off >>= 1) {
    lo += __shfl_down(lo, off, 64);
    mc += __shfl_down(mc, off, 64);
    en += __shfl_down(en, off, 64);
  }
  if (tn == 0) {
    float denom = mc * 64.0f;
    float el = lo / denom;                  // embedding_loss == commitment_loss
    out[0]      = __fadd_rn(el, __fmul_rn(0.25f, el));
    out[O_PERP] = expf(-en);
  }
}

// ---------------------------------------------------------------------------
extern "C" void kernel_launch(void* const* d_in, const int* in_sizes, int n_in,
                              void* d_out, int out_size, void* d_ws, size_t ws_size,
                              hipStream_t stream) {
  const float* z    = (const float*)d_in[0];
  const int*   mask = (const int*)d_in[1];
  const float* emb  = (const float*)d_in[2];
  float* out = (float*)d_out;
  char*  ws  = (char*)d_ws;

  unsigned long long* packed = (unsigned long long*)ws;          // 16384 * 8B
  float* s_z        = (float*)(ws + 131072);                     // 16384 * 4B
  float* s_e        = (float*)(ws + 196608);                     // 8192  * 4B
  int*   hist       = (int*)  (ws + 229376);                     // 8192  * 4B
  float* token_loss = (float*)(ws + 262144);                     // 16384 * 4B
  float* partials   = (float*)(ws + 327680);                     // 192   * 4B

  k_init<<<96, 256, 0, stream>>>(z, mask, emb, packed, s_z, s_e, hist);

  dim3 g1(32, 256, 1);   // x: 8192/256 code tiles, y: 16384/64 token tiles
  k_search<<<g1, 128, 0, stream>>>(z, mask, emb, s_z, s_e, packed, out + O_ENC);

  k_finalize<<<256, 512, 0, stream>>>(z, mask, emb, packed,
                                      out + O_ZQ, out + O_ENC, out + O_IDX,
                                      hist, token_loss);

  k_partial<<<64, 256, 0, stream>>>(token_loss, mask, hist, partials);
  k_final<<<1, 64, 0, stream>>>(partials, out);
}

// Round 5
// 9237.775 us; speedup vs baseline: 3.3032x; 3.3032x over previous
//
#include <hip/hip_runtime.h>
#include <cstdint>
#include <cstddef>

#define TOK 16384
#define NE  8192

// output layout (all float32): loss | z_q(32,64,512) | perp | enc(16384,8192) | idx(16384)
#define O_ZQ   1
#define O_PERP 1048577
#define O_ENC  1048578
#define O_IDX  135266306

// ---------------------------------------------------------------------------
// K0: s_z per token + s_e per code (numpy 8-acc pairwise), init packed/hist
// ---------------------------------------------------------------------------
__global__ __launch_bounds__(256) void k_init(
    const float* __restrict__ z, const int* __restrict__ mask,
    const float* __restrict__ emb,
    unsigned long long* __restrict__ packed,
    float* __restrict__ s_z, float* __restrict__ s_e,
    int* __restrict__ hist) {
  int g = blockIdx.x * 256 + threadIdx.x;
  if (g < TOK) {
    int t = g, b = t >> 9, l = t & 511;
    const float* zp = z + (size_t)b * 32768 + l;
    float r[8];
#pragma unroll
    for (int j = 0; j < 8; ++j) { float v = zp[(size_t)j * 512]; r[j] = __fmul_rn(v, v); }
#pragma unroll
    for (int i = 8; i < 64; i += 8)
#pragma unroll
      for (int j = 0; j < 8; ++j) { float v = zp[(size_t)(i + j) * 512]; r[j] = __fadd_rn(r[j], __fmul_rn(v, v)); }
    float s = __fadd_rn(__fadd_rn(__fadd_rn(r[0], r[1]), __fadd_rn(r[2], r[3])),
                        __fadd_rn(__fadd_rn(r[4], r[5]), __fadd_rn(r[6], r[7])));
    s_z[t] = mask[t] ? s : 0.0f;
    packed[t] = ~0ull;
  } else if (g < TOK + NE) {
    int i = g - TOK;
    const float* ep = emb + (size_t)i * 64;
    float r[8];
#pragma unroll
    for (int j = 0; j < 8; ++j) { float v = ep[j]; r[j] = __fmul_rn(v, v); }
#pragma unroll
    for (int kk = 8; kk < 64; kk += 8)
#pragma unroll
      for (int j = 0; j < 8; ++j) { float v = ep[kk + j]; r[j] = __fadd_rn(r[j], __fmul_rn(v, v)); }
    float s = __fadd_rn(__fadd_rn(__fadd_rn(r[0], r[1]), __fadd_rn(r[2], r[3])),
                        __fadd_rn(__fadd_rn(r[4], r[5]), __fadd_rn(r[6], r[7])));
    s_e[i] = s;
    hist[i] = 0;
  }
}

// ---------------------------------------------------------------------------
// K1: distance GEMM. 256 thr (16 tg x 16 cg), tile 128 tok x 128 codes,
// per-thread 8x8 (acc=64 regs; ~160 total -> no spill under bounds(256,2)).
// LDS padded [68] (R2-proven zero-conflict patterns). 69.6 KB -> 2 blocks/CU.
// thread (tg,cg): tokens tg+16m, codes cg+16j (m,j in 0..7).
// ---------------------------------------------------------------------------
__global__ __launch_bounds__(256, 2) void k_search(
    const float* __restrict__ z, const int* __restrict__ mask,
    const float* __restrict__ emb,
    const float* __restrict__ s_z, const float* __restrict__ s_e,
    unsigned long long* __restrict__ packed,
    float* __restrict__ enc_out) {
  __shared__ __align__(16) float zs[128][68];  // [token][k]
  __shared__ __align__(16) float es[128][68];  // [code][k]

  const int tid = threadIdx.x;
  const int I0  = blockIdx.x * 128;
  const int T0  = blockIdx.y * 128;
  const int b   = T0 >> 9;
  const int l0  = T0 & 511;

  // ---- stage zs: lane=token (coalesced along l), scalar LDS writes (R2 pattern)
  {
    const int lq = tid & 127;
    const int m  = mask[T0 + lq];
#pragma unroll
    for (int rep = 0; rep < 32; ++rep) {
      int c = (tid >> 7) + rep * 2;                       // 0..63
      float v = z[(size_t)b * 32768 + (size_t)c * 512 + l0 + lq];
      zs[lq][c] = m ? v : 0.0f;
    }
  }
  // ---- stage es: lane=k (coalesced along k), scalar LDS writes (R2 pattern)
  {
    const int cq = tid & 63;
#pragma unroll
    for (int rep = 0; rep < 32; ++rep) {
      int i = (tid >> 6) + rep * 4;                       // 0..127
      es[i][cq] = emb[(size_t)(I0 + i) * 64 + cq];
    }
  }
  __syncthreads();

  const int tg = tid >> 4;   // 0..15
  const int cg = tid & 15;   // 0..15

  // epilogue scalars, prefetched into regs
  float szv[8], sev[8];
#pragma unroll
  for (int m = 0; m < 8; ++m) szv[m] = s_z[T0 + tg + 16 * m];
#pragma unroll
  for (int j = 0; j < 8; ++j) sev[j] = s_e[I0 + cg + 16 * j];

  float acc[8][8];
#pragma unroll
  for (int m = 0; m < 8; ++m)
#pragma unroll
    for (int j = 0; j < 8; ++j) acc[m][j] = 0.0f;

  float* encb = enc_out + (size_t)T0 * 8192 + I0;

#pragma unroll
  for (int kc = 0; kc < 64; kc += 4) {
    float4 zv[8], ev[8];
#pragma unroll
    for (int m = 0; m < 8; ++m) zv[m] = *(const float4*)&zs[tg + 16 * m][kc];
#pragma unroll
    for (int j = 0; j < 8; ++j) ev[j] = *(const float4*)&es[cg + 16 * j][kc];

    // fused metered zero-fill of the 128x128 enc tile: 1 float4 store/chunk
    {
      int id  = (kc >> 2) * 256 + tid;   // 0..4095
      int row = id >> 5;                 // 0..127
      int c4  = id & 31;                 // 0..31
      *(float4*)(encb + (size_t)row * 8192 + c4 * 4) = make_float4(0.f, 0.f, 0.f, 0.f);
    }

#pragma unroll
    for (int m = 0; m < 8; ++m)
#pragma unroll
      for (int j = 0; j < 8; ++j) {
        acc[m][j] = fmaf(zv[m].x, ev[j].x, acc[m][j]);
        acc[m][j] = fmaf(zv[m].y, ev[j].y, acc[m][j]);
        acc[m][j] = fmaf(zv[m].z, ev[j].z, acc[m][j]);
        acc[m][j] = fmaf(zv[m].w, ev[j].w, acc[m][j]);
      }
  }

  // ---- epilogue: d = fl(fl(sz+se) - fl(2*dot)); strict-< argmin, j ascending
  float best_d[8];
  int   best_i[8];
#pragma unroll
  for (int m = 0; m < 8; ++m) { best_d[m] = __uint_as_float(0x7F800000u); best_i[m] = 0; }
#pragma unroll
  for (int j = 0; j < 8; ++j) {
    const int i = I0 + cg + 16 * j;
#pragma unroll
    for (int m = 0; m < 8; ++m) {
      float d = __fsub_rn(__fadd_rn(szv[m], sev[j]), __fmul_rn(2.0f, acc[m][j]));
      bool lt = d < best_d[m];
      best_d[m] = lt ? d : best_d[m];
      best_i[m] = lt ? i : best_i[m];
    }
  }

  // pack (ordered-bits(d)<<32 | idx); min over cg (lane bits 0..3); atomic
#pragma unroll
  for (int m = 0; m < 8; ++m) {
    unsigned int db = __float_as_uint(best_d[m]);
    db = ((int)db < 0) ? ~db : (db | 0x80000000u);
    unsigned long long p = ((unsigned long long)db << 32) | (unsigned int)best_i[m];
#pragma unroll
    for (int off = 1; off < 16; off <<= 1) {
      unsigned long long q = __shfl_xor(p, off, 64);
      p = (q < p) ? q : p;
    }
    if (cg == 0) atomicMin(&packed[T0 + tg + 16 * m], p);
  }
}

// ---------------------------------------------------------------------------
// K2: per-token finalize — coalesced (block = 64 consecutive tokens, 512 thr)
// ---------------------------------------------------------------------------
__global__ __launch_bounds__(512) void k_finalize(
    const float* __restrict__ z, const int* __restrict__ mask,
    const float* __restrict__ emb,
    const unsigned long long* __restrict__ packed,
    float* __restrict__ out_zq, float* __restrict__ out_enc,
    float* __restrict__ out_idx,
    int* __restrict__ hist, float* __restrict__ token_loss) {
  __shared__ float part[8][64];
  const int T0   = blockIdx.x * 64;
  const int lane = threadIdx.x & 63;
  const int w    = threadIdx.x >> 6;
  const int b    = T0 >> 9;
  const int l0   = T0 & 511;
  const int t    = T0 + lane;

  const int idx = (int)(unsigned int)(packed[t] & 0xFFFFFFFFu);

  const float* zb = z      + (size_t)b * 32768 + l0 + lane;
  float*       qb = out_zq + (size_t)b * 32768 + l0 + lane;

  float sq = 0.0f;
#pragma unroll
  for (int cc = 0; cc < 8; ++cc) {
    int c = w * 8 + cc;
    float zv   = zb[(size_t)c * 512];
    float e    = emb[(size_t)idx * 64 + c];
    float diff = __fsub_rn(e, zv);
    qb[(size_t)c * 512] = __fadd_rn(zv, diff);   // z + (z_q - z), bit-exact STE
    sq = fmaf(diff, diff, sq);
  }
  part[w][lane] = sq;
  __syncthreads();

  if (w == 0) {
    float s = __fadd_rn(
        __fadd_rn(__fadd_rn(part[0][lane], part[1][lane]),
                  __fadd_rn(part[2][lane], part[3][lane])),
        __fadd_rn(__fadd_rn(part[4][lane], part[5][lane]),
                  __fadd_rn(part[6][lane], part[7][lane])));
    token_loss[t] = mask[t] ? s : 0.0f;
    out_idx[t] = (float)idx;
    out_enc[(size_t)t * 8192 + idx] = 1.0f;
    atomicAdd(&hist[idx], 1);
  }
}

// ---------------------------------------------------------------------------
// K3a: partial reductions (64 blocks)
// ---------------------------------------------------------------------------
__global__ __launch_bounds__(256) void k_partial(
    const float* __restrict__ token_loss, const int* __restrict__ mask,
    const int* __restrict__ hist, float* __restrict__ partials) {
  __shared__ float sf[256], sm[256], sh[256];
  const int bb = blockIdx.x, tid = threadIdx.x;
  int ti = bb * 256 + tid;
  sf[tid] = token_loss[ti];
  sm[tid] = (float)mask[ti];
  float h = 0.f;
  if (tid < 128) {
    float pm = (float)hist[bb * 128 + tid] * (1.0f / 16384.0f);
    h = pm * logf(pm + 1e-10f);
  }
  sh[tid] = h;
  __syncthreads();
  for (int off = 128; off; off >>= 1) {
    if (tid < off) { sf[tid] += sf[tid + off]; sm[tid] += sm[tid + off]; sh[tid] += sh[tid + off]; }
    __syncthreads();
  }
  if (tid == 0) {
    partials[bb]       = sf[0];
    partials[64 + bb]  = sm[0];
    partials[128 + bb] = sh[0];
  }
}

// ---------------------------------------------------------------------------
// K3b: final scalars
// ---------------------------------------------------------------------------
__global__ __launch_bounds__(64) void k_final(
    const float* __restrict__ partials, float* __restrict__ out) {
  int tn = threadIdx.x;
  float lo = partials[tn], mc = partials[64 + tn], en = partials[128 + tn];
#pragma unroll
  for (int off = 32; off; off >>= 1) {
    lo += __shfl_down(lo, off, 64);
    mc += __shfl_down(mc, off, 64);
    en += __shfl_down(en, off, 64);
  }
  if (tn == 0) {
    float denom = mc * 64.0f;
    float el = lo / denom;                  // embedding_loss == commitment_loss
    out[0]      = __fadd_rn(el, __fmul_rn(0.25f, el));
    out[O_PERP] = expf(-en);
  }
}

// ---------------------------------------------------------------------------
extern "C" void kernel_launch(void* const* d_in, const int* in_sizes, int n_in,
                              void* d_out, int out_size, void* d_ws, size_t ws_size,
                              hipStream_t stream) {
  const float* z    = (const float*)d_in[0];
  const int*   mask = (const int*)d_in[1];
  const float* emb  = (const float*)d_in[2];
  float* out = (float*)d_out;
  char*  ws  = (char*)d_ws;

  unsigned long long* packed = (unsigned long long*)ws;          // 16384 * 8B
  float* s_z        = (float*)(ws + 131072);                     // 16384 * 4B
  float* s_e        = (float*)(ws + 196608);                     // 8192  * 4B
  int*   hist       = (int*)  (ws + 229376);                     // 8192  * 4B
  float* token_loss = (float*)(ws + 262144);                     // 16384 * 4B
  float* partials   = (float*)(ws + 327680);                     // 192   * 4B

  k_init<<<96, 256, 0, stream>>>(z, mask, emb, packed, s_z, s_e, hist);

  dim3 g1(64, 128, 1);   // x: 8192/128 code tiles, y: 16384/128 token tiles
  k_search<<<g1, 256, 0, stream>>>(z, mask, emb, s_z, s_e, packed, out + O_ENC);

  k_finalize<<<256, 512, 0, stream>>>(z, mask, emb, packed,
                                      out + O_ZQ, out + O_ENC, out + O_IDX,
                                      hist, token_loss);

  k_partial<<<64, 256, 0, stream>>>(token_loss, mask, hist, partials);
  k_final<<<1, 64, 0, stream>>>(partials, out);
}

// Round 6
// 363.731 us; speedup vs baseline: 83.8922x; 25.3973x over previous
//
#include <hip/hip_runtime.h>
#include <cstdint>
#include <cstddef>

#define TOK 16384
#define NE  8192

// output layout (all float32): loss | z_q(32,64,512) | perp | enc(16384,8192) | idx(16384)
#define O_ZQ   1
#define O_PERP 1048577
#define O_ENC  1048578
#define O_IDX  135266306

// ---------------------------------------------------------------------------
// K0: s_z per token + s_e per code (numpy 8-acc pairwise), init packed/hist
// ---------------------------------------------------------------------------
__global__ __launch_bounds__(256) void k_init(
    const float* __restrict__ z, const int* __restrict__ mask,
    const float* __restrict__ emb,
    unsigned long long* __restrict__ packed,
    float* __restrict__ s_z, float* __restrict__ s_e,
    int* __restrict__ hist) {
  int g = blockIdx.x * 256 + threadIdx.x;
  if (g < TOK) {
    int t = g, b = t >> 9, l = t & 511;
    const float* zp = z + (size_t)b * 32768 + l;
    float r[8];
#pragma unroll
    for (int j = 0; j < 8; ++j) { float v = zp[(size_t)j * 512]; r[j] = __fmul_rn(v, v); }
#pragma unroll
    for (int i = 8; i < 64; i += 8)
#pragma unroll
      for (int j = 0; j < 8; ++j) { float v = zp[(size_t)(i + j) * 512]; r[j] = __fadd_rn(r[j], __fmul_rn(v, v)); }
    float s = __fadd_rn(__fadd_rn(__fadd_rn(r[0], r[1]), __fadd_rn(r[2], r[3])),
                        __fadd_rn(__fadd_rn(r[4], r[5]), __fadd_rn(r[6], r[7])));
    s_z[t] = mask[t] ? s : 0.0f;
    packed[t] = ~0ull;
  } else if (g < TOK + NE) {
    int i = g - TOK;
    const float* ep = emb + (size_t)i * 64;
    float r[8];
#pragma unroll
    for (int j = 0; j < 8; ++j) { float v = ep[j]; r[j] = __fmul_rn(v, v); }
#pragma unroll
    for (int kk = 8; kk < 64; kk += 8)
#pragma unroll
      for (int j = 0; j < 8; ++j) { float v = ep[kk + j]; r[j] = __fadd_rn(r[j], __fmul_rn(v, v)); }
    float s = __fadd_rn(__fadd_rn(__fadd_rn(r[0], r[1]), __fadd_rn(r[2], r[3])),
                        __fadd_rn(__fadd_rn(r[4], r[5]), __fadd_rn(r[6], r[7])));
    s_e[i] = s;
    hist[i] = 0;
  }
}

// ---------------------------------------------------------------------------
// K1: distance GEMM. 256 thr (16 tg x 16 cg), tile 128 tok x 128 codes,
// per-thread 8x8. Pressure-engineered for a 128-VGPR budget:
//   - enc fill hoisted out of the loop (kernel start)
//   - s_z/s_e loads deferred to epilogue
//   - k-loop unroll 1; ev transient in 2 groups of 4
// LDS [68]-padded, 69.6 KB -> 2 blocks/CU.
// ---------------------------------------------------------------------------
__global__ __launch_bounds__(256, 2) void k_search(
    const float* __restrict__ z, const int* __restrict__ mask,
    const float* __restrict__ emb,
    const float* __restrict__ s_z, const float* __restrict__ s_e,
    unsigned long long* __restrict__ packed,
    float* __restrict__ enc_out) {
  __shared__ __align__(16) float zs[128][68];  // [token][k]
  __shared__ __align__(16) float es[128][68];  // [code][k]

  const int tid = threadIdx.x;
  const int I0  = blockIdx.x * 128;
  const int T0  = blockIdx.y * 128;
  const int b   = T0 >> 9;
  const int l0  = T0 & 511;

  // ---- fused zero-fill of the 128x128 enc tile (coalesced float4, up front)
  {
    float* encb = enc_out + (size_t)T0 * 8192 + I0;
#pragma unroll
    for (int it = 0; it < 16; ++it) {
      int id  = it * 256 + tid;          // 0..4095
      int row = id >> 5;                 // 0..127
      int c4  = id & 31;                 // 0..31
      *(float4*)(encb + (size_t)row * 8192 + c4 * 4) = make_float4(0.f, 0.f, 0.f, 0.f);
    }
  }

  // ---- stage zs: lane=token (coalesced along l), scalar LDS writes
  {
    const int lq = tid & 127;
    const int m  = mask[T0 + lq];
#pragma unroll
    for (int rep = 0; rep < 32; ++rep) {
      int c = (tid >> 7) + rep * 2;                       // 0..63
      float v = z[(size_t)b * 32768 + (size_t)c * 512 + l0 + lq];
      zs[lq][c] = m ? v : 0.0f;
    }
  }
  // ---- stage es: lane=k (coalesced along k), scalar LDS writes
  {
    const int cq = tid & 63;
#pragma unroll
    for (int rep = 0; rep < 32; ++rep) {
      int i = (tid >> 6) + rep * 4;                       // 0..127
      es[i][cq] = emb[(size_t)(I0 + i) * 64 + cq];
    }
  }
  __syncthreads();

  const int tg = tid >> 4;   // 0..15
  const int cg = tid & 15;   // 0..15

  float acc[8][8];
#pragma unroll
  for (int m = 0; m < 8; ++m)
#pragma unroll
    for (int j = 0; j < 8; ++j) acc[m][j] = 0.0f;

#pragma unroll 1
  for (int kc = 0; kc < 64; kc += 4) {
    float4 zv[8];
#pragma unroll
    for (int m = 0; m < 8; ++m) zv[m] = *(const float4*)&zs[tg + 16 * m][kc];

#pragma unroll
    for (int jj = 0; jj < 2; ++jj) {
      float4 ev[4];
#pragma unroll
      for (int q = 0; q < 4; ++q) ev[q] = *(const float4*)&es[cg + 16 * (jj * 4 + q)][kc];
#pragma unroll
      for (int m = 0; m < 8; ++m)
#pragma unroll
        for (int q = 0; q < 4; ++q) {
          const int j = jj * 4 + q;
          acc[m][j] = fmaf(zv[m].x, ev[q].x, acc[m][j]);
          acc[m][j] = fmaf(zv[m].y, ev[q].y, acc[m][j]);
          acc[m][j] = fmaf(zv[m].z, ev[q].z, acc[m][j]);
          acc[m][j] = fmaf(zv[m].w, ev[q].w, acc[m][j]);
        }
    }
  }

  // ---- epilogue: load scalars now (frees in-loop regs); d = fl(fl(sz+se)-fl(2*dot))
  float szv[8], sev[8];
#pragma unroll
  for (int m = 0; m < 8; ++m) szv[m] = s_z[T0 + tg + 16 * m];
#pragma unroll
  for (int j = 0; j < 8; ++j) sev[j] = s_e[I0 + cg + 16 * j];

  float best_d[8];
  int   best_i[8];
#pragma unroll
  for (int m = 0; m < 8; ++m) { best_d[m] = __uint_as_float(0x7F800000u); best_i[m] = 0; }
#pragma unroll
  for (int j = 0; j < 8; ++j) {
    const int i = I0 + cg + 16 * j;
#pragma unroll
    for (int m = 0; m < 8; ++m) {
      float d = __fsub_rn(__fadd_rn(szv[m], sev[j]), __fmul_rn(2.0f, acc[m][j]));
      bool lt = d < best_d[m];
      best_d[m] = lt ? d : best_d[m];
      best_i[m] = lt ? i : best_i[m];
    }
  }

  // pack (ordered-bits(d)<<32 | idx); min over cg (lane bits 0..3); atomic
#pragma unroll
  for (int m = 0; m < 8; ++m) {
    unsigned int db = __float_as_uint(best_d[m]);
    db = ((int)db < 0) ? ~db : (db | 0x80000000u);
    unsigned long long p = ((unsigned long long)db << 32) | (unsigned int)best_i[m];
#pragma unroll
    for (int off = 1; off < 16; off <<= 1) {
      unsigned long long q = __shfl_xor(p, off, 64);
      p = (q < p) ? q : p;
    }
    if (cg == 0) atomicMin(&packed[T0 + tg + 16 * m], p);
  }
}

// ---------------------------------------------------------------------------
// K2: per-token finalize — coalesced (block = 64 consecutive tokens, 512 thr)
// ---------------------------------------------------------------------------
__global__ __launch_bounds__(512) void k_finalize(
    const float* __restrict__ z, const int* __restrict__ mask,
    const float* __restrict__ emb,
    const unsigned long long* __restrict__ packed,
    float* __restrict__ out_zq, float* __restrict__ out_enc,
    float* __restrict__ out_idx,
    int* __restrict__ hist, float* __restrict__ token_loss) {
  __shared__ float part[8][64];
  const int T0   = blockIdx.x * 64;
  const int lane = threadIdx.x & 63;
  const int w    = threadIdx.x >> 6;
  const int b    = T0 >> 9;
  const int l0   = T0 & 511;
  const int t    = T0 + lane;

  const int idx = (int)(unsigned int)(packed[t] & 0xFFFFFFFFu);

  const float* zb = z      + (size_t)b * 32768 + l0 + lane;
  float*       qb = out_zq + (size_t)b * 32768 + l0 + lane;

  float sq = 0.0f;
#pragma unroll
  for (int cc = 0; cc < 8; ++cc) {
    int c = w * 8 + cc;
    float zv   = zb[(size_t)c * 512];
    float e    = emb[(size_t)idx * 64 + c];
    float diff = __fsub_rn(e, zv);
    qb[(size_t)c * 512] = __fadd_rn(zv, diff);   // z + (z_q - z), bit-exact STE
    sq = fmaf(diff, diff, sq);
  }
  part[w][lane] = sq;
  __syncthreads();

  if (w == 0) {
    float s = __fadd_rn(
        __fadd_rn(__fadd_rn(part[0][lane], part[1][lane]),
                  __fadd_rn(part[2][lane], part[3][lane])),
        __fadd_rn(__fadd_rn(part[4][lane], part[5][lane]),
                  __fadd_rn(part[6][lane], part[7][lane])));
    token_loss[t] = mask[t] ? s : 0.0f;
    out_idx[t] = (float)idx;
    out_enc[(size_t)t * 8192 + idx] = 1.0f;
    atomicAdd(&hist[idx], 1);
  }
}

// ---------------------------------------------------------------------------
// K3a: partial reductions (64 blocks)
// ---------------------------------------------------------------------------
__global__ __launch_bounds__(256) void k_partial(
    const float* __restrict__ token_loss, const int* __restrict__ mask,
    const int* __restrict__ hist, float* __restrict__ partials) {
  __shared__ float sf[256], sm[256], sh[256];
  const int bb = blockIdx.x, tid = threadIdx.x;
  int ti = bb * 256 + tid;
  sf[tid] = token_loss[ti];
  sm[tid] = (float)mask[ti];
  float h = 0.f;
  if (tid < 128) {
    float pm = (float)hist[bb * 128 + tid] * (1.0f / 16384.0f);
    h = pm * logf(pm + 1e-10f);
  }
  sh[tid] = h;
  __syncthreads();
  for (int off = 128; off; off >>= 1) {
    if (tid < off) { sf[tid] += sf[tid + off]; sm[tid] += sm[tid + off]; sh[tid] += sh[tid + off]; }
    __syncthreads();
  }
  if (tid == 0) {
    partials[bb]       = sf[0];
    partials[64 + bb]  = sm[0];
    partials[128 + bb] = sh[0];
  }
}

// ---------------------------------------------------------------------------
// K3b: final scalars
// ---------------------------------------------------------------------------
__global__ __launch_bounds__(64) void k_final(
    const float* __restrict__ partials, float* __restrict__ out) {
  int tn = threadIdx.x;
  float lo = partials[tn], mc = partials[64 + tn], en = partials[128 + tn];
#pragma unroll
  for (int off = 32; off; off >>= 1) {
    lo += __shfl_down(lo, off, 64);
    mc += __shfl_down(mc, off, 64);
    en += __shfl_down(en, off, 64);
  }
  if (tn == 0) {
    float denom = mc * 64.0f;
    float el = lo / denom;                  // embedding_loss == commitment_loss
    out[0]      = __fadd_rn(el, __fmul_rn(0.25f, el));
    out[O_PERP] = expf(-en);
  }
}

// ---------------------------------------------------------------------------
extern "C" void kernel_launch(void* const* d_in, const int* in_sizes, int n_in,
                              void* d_out, int out_size, void* d_ws, size_t ws_size,
                              hipStream_t stream) {
  const float* z    = (const float*)d_in[0];
  const int*   mask = (const int*)d_in[1];
  const float* emb  = (const float*)d_in[2];
  float* out = (float*)d_out;
  char*  ws  = (char*)d_ws;

  unsigned long long* packed = (unsigned long long*)ws;          // 16384 * 8B
  float* s_z        = (float*)(ws + 131072);                     // 16384 * 4B
  float* s_e        = (float*)(ws + 196608);                     // 8192  * 4B
  int*   hist       = (int*)  (ws + 229376);                     // 8192  * 4B
  float* token_loss = (float*)(ws + 262144);                     // 16384 * 4B
  float* partials   = (float*)(ws + 327680);                     // 192   * 4B

  k_init<<<96, 256, 0, stream>>>(z, mask, emb, packed, s_z, s_e, hist);

  dim3 g1(64, 128, 1);   // x: 8192/128 code tiles, y: 16384/128 token tiles
  k_search<<<g1, 256, 0, stream>>>(z, mask, emb, s_z, s_e, packed, out + O_ENC);

  k_finalize<<<256, 512, 0, stream>>>(z, mask, emb, packed,
                                      out + O_ZQ, out + O_ENC, out + O_IDX,
                                      hist, token_loss);

  k_partial<<<64, 256, 0, stream>>>(token_loss, mask, hist, partials);
  k_final<<<1, 64, 0, stream>>>(partials, out);
}